// Round 11
// baseline (194.244 us; speedup 1.0000x reference)
//
#include <hip/hip_runtime.h>
#include <stdint.h>

// Problem constants: B=2, S=2048, H=1024, NH=16, HD=64, K=1024
// Inputs FP32 -> one cvt pass to bf16 -> bf16 MFMA pipeline -> output FP32.

typedef __attribute__((ext_vector_type(8))) short short8;
typedef __attribute__((ext_vector_type(4))) float floatx4;
typedef __attribute__((ext_vector_type(4))) unsigned int uint4v;
typedef __attribute__((ext_vector_type(2))) unsigned int uint2v;

__device__ __forceinline__ unsigned short f2bf(float f) {          // RNE
    unsigned int u = __float_as_uint(f);
    unsigned int r = u + 0x7fffu + ((u >> 16) & 1u);
    return (unsigned short)(r >> 16);
}
// pack two fp32 -> bf16x2 dword
#if __has_builtin(__builtin_amdgcn_cvt_pk_bf16_f32)
__device__ __forceinline__ unsigned int pack_bf2(float lo, float hi) {
    auto v = __builtin_amdgcn_cvt_pk_bf16_f32(lo, hi);
    return __builtin_bit_cast(unsigned int, v);
}
#else
__device__ __forceinline__ unsigned int pack_bf2(float lo, float hi) {
    unsigned int a = __float_as_uint(lo) + 0x8000u;
    unsigned int b = __float_as_uint(hi) + 0x8000u;
    return __builtin_amdgcn_perm(b, a, 0x07060302u);
}
#endif

// raw exp2 (v_exp_f32) when available
#if __has_builtin(__builtin_amdgcn_exp2f)
#define EXP2(x) __builtin_amdgcn_exp2f(x)
#else
#define EXP2(x) exp2f(x)
#endif

// async global->LDS, 16B per lane. LDS dest: wave-uniform base + lane*16.
__device__ __forceinline__ void gl2lds16(const void* g, void* l) {
    __builtin_amdgcn_global_load_lds(
        (const __attribute__((address_space(1))) unsigned int*)g,
        (__attribute__((address_space(3))) unsigned int*)l, 16, 0, 0);
}

#define MFMA32(a, b, c) __builtin_amdgcn_mfma_f32_16x16x32_bf16((a), (b), (c), 0, 0, 0)

// ---------------------------------------------------------------------------
// One-pass prep: fp32->bf16 for hidden / w_qkv / w_out, plus mask transform
// m2 = mask*log2(e) - 10*log2(e) (fp32). Grid exactly 8196 x 256.
// ---------------------------------------------------------------------------
__global__ __launch_bounds__(256)
void cvt_all(const float* __restrict__ a, const float* __restrict__ b,
             const float* __restrict__ c, const float* __restrict__ mask,
             unsigned short* __restrict__ oa, unsigned short* __restrict__ ob,
             unsigned short* __restrict__ oc, float* __restrict__ m2b)
{
    int i = blockIdx.x * 256 + threadIdx.x;
    if (i >= 2097152) {                     // mask range: 1024 groups
        int off = i - 2097152;
        float4 v = *(const float4*)(mask + (size_t)off * 4);
        const float L2E = 1.44269504f, C2 = -14.4269504f;
        float4 w;
        w.x = fmaf(v.x, L2E, C2); w.y = fmaf(v.y, L2E, C2);
        w.z = fmaf(v.z, L2E, C2); w.w = fmaf(v.w, L2E, C2);
        *(float4*)(m2b + (size_t)off * 4) = w;
        return;
    }
    const float* src; unsigned short* dst; int off;
    if (i < 1048576)      { src = a; dst = oa; off = i; }
    else if (i < 1835008) { src = b; dst = ob; off = i - 1048576; }
    else                  { src = c; dst = oc; off = i - 1835008; }
    float4 v = *(const float4*)(src + (size_t)off * 4);
    uint2v w;
    w[0] = pack_bf2(v.x, v.y);
    w[1] = pack_bf2(v.z, v.w);
    *(uint2v*)(dst + (size_t)off * 4) = w;
}

// ---------------------------------------------------------------------------
// NT GEMM v3 (verified rounds 8-10: out of the top-5, was ~75us):
// 128 x BN tile, BK=32, 4 waves (2x2) x (64 x BN/2).
// TRIPLE-buffered LDS + depth-2 prefetch + counted vmcnt; 48KB LDS ->
// 3 blocks/CU, grid 768 fully resident; stage(t) gets ~2 compute phases.
// LDS layout: 128B paired-row lines (2 M-rows x 64B), 8x16B slots XOR-
// swizzled by (line&7) -> 0 measured bank conflicts. Stage side pre-swizzles
// the GLOBAL source address; LDS dest stays linear (gl2lds requirement).
// MODE 0: scatter bf16 to q/k ([B,NH,S,HD]) + V^T ([B,NH,HD,S'])
//         S' key-interleaved within 32-groups:
//         k' = (k&~31) | ((k>>2)&3)<<3 | ((k>>4)&1)<<2 | (k&3).
//         q PRE-SCALED by 0.125*log2(e) so attn exp2's the raw MFMA out.
// MODE 1: fp32 store outf[m*N+n].
// ---------------------------------------------------------------------------
template<int MODE, int BN>
__global__ __launch_bounds__(256)
void gemm_nt(const unsigned short* __restrict__ A,
             const unsigned short* __restrict__ Bm,
             unsigned short* __restrict__ out0,
             unsigned short* __restrict__ out1,
             unsigned short* __restrict__ out2,
             float* __restrict__ outf,
             int N)
{
    constexpr int BUFB  = 8192 + BN * 64;        // bytes per buffer (A + B)
    constexpr int NSTEP = 32;                    // K / 32
    constexpr int NA    = 2;                     // A DMAs per wave per stage
    constexpr int NB    = BN / 64;               // B DMAs per wave per stage
    constexpr int BSL   = BN / 32;
    __shared__ unsigned char smem[3 * BUFB];
    const int K = 1024;
    const int tid  = threadIdx.x;
    const int wave = tid >> 6, lane = tid & 63;
    const int l15  = lane & 15, quad = lane >> 4;
    const int wm = wave >> 1, wn = wave & 1;

    int Lid = blockIdx.y * gridDim.x + blockIdx.x;
    int bm = (Lid & 7) * 4 + ((Lid >> 3) & 3);
    int bn = Lid >> 5;

    floatx4 acc[4][BSL];
#pragma unroll
    for (int i = 0; i < 4; i++)
#pragma unroll
        for (int j = 0; j < BSL; j++)
            acc[i][j] = floatx4{0.f, 0.f, 0.f, 0.f};

    // staging maps: chunk s (16B units) -> LDS line L = s>>3, slot p = s&7.
    // content q = p ^ (L&7): global (Mrow = L*2 + (q>>2), Kblk = q&3).
    int soffA[NA], soffB[NB];
#pragma unroll
    for (int l = 0; l < NA; l++) {
        int s = (wave * NA + l) * 64 + lane;
        int L = s >> 3, q = (s & 7) ^ (L & 7);
        soffA[l] = (L * 2 + (q >> 2)) * K + (q & 3) * 8;
    }
#pragma unroll
    for (int l = 0; l < NB; l++) {
        int s = (wave * NB + l) * 64 + lane;
        int L = s >> 3, q = (s & 7) ^ (L & 7);
        soffB[l] = (L * 2 + (q >> 2)) * K + (q & 3) * 8;
    }
    // read maps: row r, K-block quad -> line r>>1, slot (((r&1)<<2)|quad)^(line&7)
    int aoff[4], boff[BSL];
#pragma unroll
    for (int i = 0; i < 4; i++) {
        int r = wm * 64 + i * 16 + l15, L = r >> 1;
        aoff[i] = L * 128 + (((((r & 1) << 2) | quad) ^ (L & 7)) * 16);
    }
#pragma unroll
    for (int j = 0; j < BSL; j++) {
        int r = wn * (BN / 2) + j * 16 + l15, L = r >> 1;
        boff[j] = 8192 + L * 128 + (((((r & 1) << 2) | quad) ^ (L & 7)) * 16);
    }

    const unsigned short* Abase = A  + (size_t)(bm * 128) * K;
    const unsigned short* Bbase = Bm + (size_t)(bn * BN) * K;

    auto STAGE = [&](int u, int bufb) {
        const int k0 = u * 32;
#pragma unroll
        for (int l = 0; l < NA; l++)
            gl2lds16(Abase + (size_t)soffA[l] + k0, &smem[bufb + (wave * NA + l) * 1024]);
#pragma unroll
        for (int l = 0; l < NB; l++)
            gl2lds16(Bbase + (size_t)soffB[l] + k0, &smem[bufb + 8192 + (wave * NB + l) * 1024]);
    };

    // prologue: stages 0,1 into buffers 0,1
    STAGE(0, 0);
    STAGE(1, BUFB);

    int b0 = 0, b2 = 2;                          // compute buf, stage buf
    for (int t = 0; t < NSTEP; t++) {
        // barrier 1: all waves done computing step t-1 -> buf[b2] reusable
        asm volatile("" ::: "memory");
        __builtin_amdgcn_s_barrier();
        asm volatile("" ::: "memory");
        if (t + 2 < NSTEP) {
            STAGE(t + 2, b2 * BUFB);
            // retire stage(t); stages t+1,t+2 (2*NDMA) stay in flight
            if (BN == 128) asm volatile("s_waitcnt vmcnt(8)" ::: "memory");
            else           asm volatile("s_waitcnt vmcnt(6)" ::: "memory");
        } else if (t + 2 == NSTEP) {
            if (BN == 128) asm volatile("s_waitcnt vmcnt(4)" ::: "memory");
            else           asm volatile("s_waitcnt vmcnt(3)" ::: "memory");
        } else {
            asm volatile("s_waitcnt vmcnt(0)" ::: "memory");
        }
        // barrier 2: tile t visible block-wide
        __builtin_amdgcn_s_barrier();
        asm volatile("" ::: "memory");

        const int cb = b0 * BUFB;
        short8 af[4], bfr[BSL];
#pragma unroll
        for (int i = 0; i < 4; i++)
            af[i] = *(const short8*)(&smem[cb + aoff[i]]);
#pragma unroll
        for (int j = 0; j < BSL; j++)
            bfr[j] = *(const short8*)(&smem[cb + boff[j]]);
#pragma unroll
        for (int i = 0; i < 4; i++)
#pragma unroll
            for (int j = 0; j < BSL; j++)
                acc[i][j] = MFMA32(af[i], bfr[j], acc[i][j]);

        b0 = (b0 == 2) ? 0 : b0 + 1;
        b2 = (b2 == 2) ? 0 : b2 + 1;
    }

#pragma unroll
    for (int i = 0; i < 4; i++) {
#pragma unroll
        for (int j = 0; j < BSL; j++) {
            int n = bn * BN + wn * (BN / 2) + j * 16 + l15;
#pragma unroll
            for (int r = 0; r < 4; r++) {
                int m = bm * 128 + wm * 64 + i * 16 + quad * 4 + r;
                float fv = acc[i][j][r];
                if (MODE == 1) {
                    outf[(size_t)m * N + n] = fv;
                } else {
                    int t = n >> 10;            // 0=q 1=k 2=v
                    int h = (n >> 6) & 15;
                    int d = n & 63;
                    int b = m >> 11, si = m & 2047;
                    if (t == 2) {
                        // V^T with key interleave within 32-groups
                        int sip = (si & ~31) | (((si >> 2) & 3) << 3)
                                | (((si >> 4) & 1) << 2) | (si & 3);
                        out2[(((size_t)(b * 16 + h)) * 64 + d) * 2048 + sip] = f2bf(fv);
                    } else {
                        // q pre-scaled by 0.125*log2(e) (softmax fold)
                        if (t == 0) fv *= 0.18033688f;
                        size_t off = (((size_t)(b * 16 + h)) * 2048 + si) * 64 + d;
                        unsigned short* dst = (t == 0) ? out0 : out1;
                        dst[off] = f2bf(fv);
                    }
                }
            }
        }
    }
}

// ---------------------------------------------------------------------------
// Flash attention v14 — sync-granularity attack (round-10 lessons):
//  * v13's explicit SW pipeline REVERTED (rotation v_movs raised VALUBusy
//    35->50% for 0 MFMA gain).
//  * v12's verified pieces kept: 32 q-rows/wave, conflict-free K AND V
//    layouts (0 bank conflicts), staged double-buffer + counted vmcnt,
//    exp2 on raw MFMA out, mask in QK C-init.
//  * NEW: KVBLK=64 — barrier pairs 128 -> 64, MFMA per sync region 18 -> 36,
//    16 batch-issued ds_read_b128 per region (ILP for the scheduler).
//  * NEW: 128-thread blocks (2 waves x 32q = 64 q-rows) — grid 1024,
//    4 blocks/CU (vs v12's 2), 2-wave barrier domains, 2x independent DMA
//    streams per CU. LDS 2 x 16KB = 32KB.
//  * T5: s_setprio(1) around the QK and PV MFMA clusters (m191: +4-7%).
// K tile [64key][128B-row], V tile [64d][128B-row], both with the verified
// row-XOR slot swizzle (identical read formula qkoff). Staging pre-swizzles
// the GLOBAL source; LDS dest linear (gl2lds requirement).
// vmcnt ledger/wave: stage = 8 DMAs, mf = 4 loads. Iter i: mf(4), barrier1,
// stage(i+1)(8), vmcnt(8) [retires stage(i)+mf(i), keeps stage(i+1)],
// barrier2, compute. Tail i=31: vmcnt(0).
// ---------------------------------------------------------------------------
__global__ __launch_bounds__(128, 2)
void attn_kernel(const unsigned short* __restrict__ Qb,
                 const unsigned short* __restrict__ Kb,
                 const unsigned short* __restrict__ VbT,
                 const float* __restrict__ m2b,
                 const float* __restrict__ gateb,
                 unsigned short* __restrict__ ctx)
{
    __shared__ unsigned char smem[32768];        // 2 x (K 8KB + V 8KB)
    const int S = 2048;
    const int tid  = threadIdx.x;
    const int wave = tid >> 6, lane = tid & 63;
    const int l15  = lane & 15, quad = lane >> 4;

    int Lid = blockIdx.y * gridDim.x + blockIdx.x;
    int bh = (Lid & 7) * 4 + ((Lid >> 3) & 3);   // [0,32)
    int qc = Lid >> 5;                           // [0,32): 64 q-rows/block
    const int b = bh >> 4, h = bh & 15;
    const int q0 = qc * 64 + wave * 32;          // this wave's 32 q-rows

    const size_t headoff = (size_t)bh * S * 64;
    const unsigned short* Qh  = Qb  + headoff;   // [S][64] (pre-scaled)
    const unsigned short* Kh  = Kb  + headoff;   // [S][64]
    const unsigned short* VhT = VbT + headoff;   // [64][S'] key-interleaved
    const float* m2p = m2b + (size_t)b * S;

    // staging maps (s = (wave*4+l)*64 + lane covers 512 16B-chunks of each
    // 8KB section): line L = s>>3 (K: key row / V: d row, both 128B),
    // slot p = s&7, content chunk c = p^(L&7).
    // K src: (kb+L)*64 + c*8 ; V src: L*2048 + kb + c*8.
    int koff[4], voff[4];
#pragma unroll
    for (int l = 0; l < 4; l++) {
        int s = (wave * 4 + l) * 64 + lane;
        int L = s >> 3, c = (s & 7) ^ (L & 7);
        koff[l] = L * 64 + c * 8;
        voff[l] = L * 2048 + c * 8;
    }
    // read map (shared by K and V: 128B rows, row-XOR slots — the verified
    // 0-conflict geometry): row r=l15 within a 16-row subtile, col-chunk j:
    // qkoff[j] = l15*128 + ((j*4+quad) ^ (l15&7))*16 ; add kt*2048 (K) or
    // 8192 + dt*2048 (V).
    int qkoff[2];
#pragma unroll
    for (int j = 0; j < 2; j++)
        qkoff[j] = l15 * 128 + (((j * 4 + quad) ^ (l15 & 7)) * 16);

    // Q B-frags: aq[sub][s2] = Q[q0+sub*16+l15][s2*32+quad*8+..]
    short8 aq[2][2];
#pragma unroll
    for (int sub = 0; sub < 2; sub++)
#pragma unroll
        for (int s2 = 0; s2 < 2; s2++)
            aq[sub][s2] = *(const short8*)(Qh + (size_t)(q0 + sub * 16 + l15) * 64 + s2 * 32 + quad * 8);

    floatx4 o[2][4];                 // O^T partial [sub][dt]
    floatx4 lq[2];                   // l partial [sub]
#pragma unroll
    for (int sub = 0; sub < 2; sub++) {
        lq[sub] = floatx4{0.f, 0.f, 0.f, 0.f};
#pragma unroll
        for (int dt = 0; dt < 4; dt++) o[sub][dt] = floatx4{0.f, 0.f, 0.f, 0.f};
    }

    const uint4v onesu = {0x3F803F80u, 0x3F803F80u, 0x3F803F80u, 0x3F803F80u};
    const short8 ONES = __builtin_bit_cast(short8, onesu);

    // prologue: stage chunk 0 (keys 0..63) into buffer 0
#pragma unroll
    for (int l = 0; l < 4; l++) {
        gl2lds16(Kh + koff[l], &smem[(wave * 4 + l) * 1024]);
        gl2lds16(VhT + voff[l], &smem[8192 + (wave * 4 + l) * 1024]);
    }

    for (int i = 0; i < 32; i++) {
        const int cb = (i & 1) * 16384;
        const int nb = ((i + 1) & 1) * 16384;
        const int kb = i * 64;
        // mask addends for the 4 key sub-tiles (QK C-init: row == quad*4+r)
        floatx4 mf[4];
#pragma unroll
        for (int t = 0; t < 4; t++)
            mf[t] = *(const floatx4*)(m2p + kb + t * 16 + quad * 4);
        asm volatile("" ::: "memory");
        // barrier 1: both waves done reading buf[nb] (iter i-1)
        __builtin_amdgcn_s_barrier();
        asm volatile("" ::: "memory");
        if (i + 1 < 32) {
            const int kbn = (i + 1) * 64;
#pragma unroll
            for (int l = 0; l < 4; l++) {
                gl2lds16(Kh + (size_t)kbn * 64 + koff[l], &smem[nb + (wave * 4 + l) * 1024]);
                gl2lds16(VhT + kbn + voff[l], &smem[nb + 8192 + (wave * 4 + l) * 1024]);
            }
            // retire stage(i)+mf(i); stage(i+1)'s 8 stay in flight
            asm volatile("s_waitcnt vmcnt(8)" ::: "memory");
        } else {
            asm volatile("s_waitcnt vmcnt(0)" ::: "memory");
        }
        // barrier 2: whole chunk i visible block-wide
        __builtin_amdgcn_s_barrier();
        asm volatile("" ::: "memory");

        // K frags (consumed by QK before vf loads -> bounded reg pressure)
        short8 kf[4][2];
#pragma unroll
        for (int kt = 0; kt < 4; kt++)
#pragma unroll
            for (int s2 = 0; s2 < 2; s2++)
                kf[kt][s2] = *(const short8*)(&smem[cb + kt * 2048 + qkoff[s2]]);

        // QK for both subs: st[sub][kt], C init = mask addend
        floatx4 st[2][4];
        __builtin_amdgcn_s_setprio(1);
#pragma unroll
        for (int sub = 0; sub < 2; sub++)
#pragma unroll
            for (int kt = 0; kt < 4; kt++) {
                st[sub][kt] = MFMA32(kf[kt][0], aq[sub][0], mf[kt]);
                st[sub][kt] = MFMA32(kf[kt][1], aq[sub][1], st[sub][kt]);
            }
        __builtin_amdgcn_s_setprio(0);

        // V frags (128B-row swizzle, interleaved key positions)
        short8 vf[4][2];
#pragma unroll
        for (int dt = 0; dt < 4; dt++)
#pragma unroll
            for (int g = 0; g < 2; g++)
                vf[dt][g] = *(const short8*)(&smem[cb + 8192 + dt * 2048 + qkoff[g]]);

        // exp + pack (Q pre-scaled, mask in C-init): pf[sub][g] covers the
        // 32-key group g in interleave order {t0 e0..e3, t1 e0..e3}
        short8 pf[2][2];
#pragma unroll
        for (int sub = 0; sub < 2; sub++)
#pragma unroll
            for (int g = 0; g < 2; g++) {
                floatx4 a = st[sub][2 * g], c = st[sub][2 * g + 1];
                uint4v pu = {pack_bf2(EXP2(a[0]), EXP2(a[1])),
                             pack_bf2(EXP2(a[2]), EXP2(a[3])),
                             pack_bf2(EXP2(c[0]), EXP2(c[1])),
                             pack_bf2(EXP2(c[2]), EXP2(c[3]))};
                pf[sub][g] = __builtin_bit_cast(short8, pu);
            }

        // PV + l: full-K=32 per group, un-padded
        __builtin_amdgcn_s_setprio(1);
#pragma unroll
        for (int sub = 0; sub < 2; sub++)
#pragma unroll
            for (int g = 0; g < 2; g++) {
#pragma unroll
                for (int dt = 0; dt < 4; dt++)
                    o[sub][dt] = MFMA32(vf[dt][g], pf[sub][g], o[sub][dt]);
                lq[sub] = MFMA32(ONES, pf[sub][g], lq[sub]);
            }
        __builtin_amdgcn_s_setprio(0);
    }

    // epilogue: wave-complete softmax; lane writes q = q0+sub*16+l15, all dt
    float g = gateb[h];
#pragma unroll
    for (int sub = 0; sub < 2; sub++) {
        float iv = g / lq[sub][0];
        size_t base = ((size_t)(b * 2048 + q0 + sub * 16 + l15)) * 1024 + h * 64 + quad * 4;
#pragma unroll
        for (int dt = 0; dt < 4; dt++) {
            uint2v w;
            w[0] = pack_bf2(o[sub][dt][0] * iv, o[sub][dt][1] * iv);
            w[1] = pack_bf2(o[sub][dt][2] * iv, o[sub][dt][3] * iv);
            *(uint2v*)(ctx + base + dt * 16) = w;
        }
    }
}

// ---------------------------------------------------------------------------
extern "C" void kernel_launch(void* const* d_in, const int* in_sizes, int n_in,
                              void* d_out, int out_size, void* d_ws, size_t ws_size,
                              hipStream_t stream)
{
    const float* hidden = (const float*)d_in[0]; // [2,2048,1024] fp32
    const float* mask   = (const float*)d_in[1]; // [2,1,1,2048]  fp32
    const float* w_qkv  = (const float*)d_in[2]; // [3072,1024]   fp32
    const float* w_out  = (const float*)d_in[3]; // [1024,1024]   fp32
    const float* gate   = (const float*)d_in[4]; // [16]          fp32
    float* out = (float*)d_out;                  // [2,2048,1024] fp32

    unsigned short* q_buf = (unsigned short*)d_ws;   // [2,16,2048,64] bf16 (pre-scaled)
    unsigned short* k_buf = q_buf + 4194304;         // [2,16,2048,64]
    unsigned short* v_buf = k_buf + 4194304;         // [2,16,64,2048] (V^T, interleaved)
    unsigned short* c_buf = v_buf + 4194304;         // [2,2048,1024]  bf16
    unsigned short* h_bf  = c_buf + 4194304;         // hidden bf16
    unsigned short* wq_bf = h_bf  + 4194304;         // w_qkv bf16
    unsigned short* wo_bf = wq_bf + 3145728;         // w_out bf16
    float* m2_buf = (float*)(wo_bf + 1048576);       // [2,2048] fp32

    // one-pass prep: fp32->bf16 converts + mask transform
    cvt_all<<<8196, 256, 0, stream>>>(hidden, w_qkv, w_out, mask,
                                      h_bf, wq_bf, wo_bf, m2_buf);

    // QKV projection, scatter q(pre-scaled)/k/V^T(interleaved)
    gemm_nt<0, 128><<<dim3(24, 32), 256, 0, stream>>>(h_bf, wq_bf, q_buf, k_buf, v_buf, nullptr, 3072);
    // fused flash attention + gate -> ctx bf16 (64-q blocks of 2 waves, grid 1024)
    attn_kernel<<<dim3(32, 32), 128, 0, stream>>>(q_buf, k_buf, v_buf, m2_buf, gate, c_buf);
    // output projection -> out fp32 (grid 16x32, 128x64 tiles)
    gemm_nt<1, 64><<<dim3(16, 32), 256, 0, stream>>>(c_buf, wo_bf, nullptr, nullptr, nullptr, out, 1024);
}

// Round 12
// 182.630 us; speedup vs baseline: 1.0636x; 1.0636x over previous
//
#include <hip/hip_runtime.h>
#include <stdint.h>

// Problem constants: B=2, S=2048, H=1024, NH=16, HD=64, K=1024
// Inputs FP32 -> one cvt pass to bf16 -> bf16 MFMA pipeline -> output FP32.

typedef __attribute__((ext_vector_type(8))) short short8;
typedef __attribute__((ext_vector_type(4))) float floatx4;
typedef __attribute__((ext_vector_type(4))) unsigned int uint4v;
typedef __attribute__((ext_vector_type(2))) unsigned int uint2v;

__device__ __forceinline__ unsigned short f2bf(float f) {          // RNE
    unsigned int u = __float_as_uint(f);
    unsigned int r = u + 0x7fffu + ((u >> 16) & 1u);
    return (unsigned short)(r >> 16);
}
// pack two fp32 -> bf16x2 dword
#if __has_builtin(__builtin_amdgcn_cvt_pk_bf16_f32)
__device__ __forceinline__ unsigned int pack_bf2(float lo, float hi) {
    auto v = __builtin_amdgcn_cvt_pk_bf16_f32(lo, hi);
    return __builtin_bit_cast(unsigned int, v);
}
#else
__device__ __forceinline__ unsigned int pack_bf2(float lo, float hi) {
    unsigned int a = __float_as_uint(lo) + 0x8000u;
    unsigned int b = __float_as_uint(hi) + 0x8000u;
    return __builtin_amdgcn_perm(b, a, 0x07060302u);
}
#endif

// raw exp2 (v_exp_f32) when available
#if __has_builtin(__builtin_amdgcn_exp2f)
#define EXP2(x) __builtin_amdgcn_exp2f(x)
#else
#define EXP2(x) exp2f(x)
#endif

// async global->LDS, 16B per lane. LDS dest: wave-uniform base + lane*16.
__device__ __forceinline__ void gl2lds16(const void* g, void* l) {
    __builtin_amdgcn_global_load_lds(
        (const __attribute__((address_space(1))) unsigned int*)g,
        (__attribute__((address_space(3))) unsigned int*)l, 16, 0, 0);
}

#define MFMA32(a, b, c) __builtin_amdgcn_mfma_f32_16x16x32_bf16((a), (b), (c), 0, 0, 0)

// ---------------------------------------------------------------------------
// One-pass prep: fp32->bf16 for hidden / w_qkv / w_out, plus mask transform
// m2 = mask*log2(e) - 10*log2(e) (fp32). Grid exactly 8196 x 256.
// ---------------------------------------------------------------------------
__global__ __launch_bounds__(256)
void cvt_all(const float* __restrict__ a, const float* __restrict__ b,
             const float* __restrict__ c, const float* __restrict__ mask,
             unsigned short* __restrict__ oa, unsigned short* __restrict__ ob,
             unsigned short* __restrict__ oc, float* __restrict__ m2b)
{
    int i = blockIdx.x * 256 + threadIdx.x;
    if (i >= 2097152) {                     // mask range: 1024 groups
        int off = i - 2097152;
        float4 v = *(const float4*)(mask + (size_t)off * 4);
        const float L2E = 1.44269504f, C2 = -14.4269504f;
        float4 w;
        w.x = fmaf(v.x, L2E, C2); w.y = fmaf(v.y, L2E, C2);
        w.z = fmaf(v.z, L2E, C2); w.w = fmaf(v.w, L2E, C2);
        *(float4*)(m2b + (size_t)off * 4) = w;
        return;
    }
    const float* src; unsigned short* dst; int off;
    if (i < 1048576)      { src = a; dst = oa; off = i; }
    else if (i < 1835008) { src = b; dst = ob; off = i - 1048576; }
    else                  { src = c; dst = oc; off = i - 1835008; }
    float4 v = *(const float4*)(src + (size_t)off * 4);
    uint2v w;
    w[0] = pack_bf2(v.x, v.y);
    w[1] = pack_bf2(v.z, v.w);
    *(uint2v*)(dst + (size_t)off * 4) = w;
}

// ---------------------------------------------------------------------------
// NT GEMM v3 (verified rounds 8-11: out of the top-5, was ~75us):
// 128 x BN tile, BK=32, 4 waves (2x2) x (64 x BN/2).
// TRIPLE-buffered LDS + depth-2 prefetch + counted vmcnt; 48KB LDS ->
// 3 blocks/CU, grid 768 fully resident; stage(t) gets ~2 compute phases.
// LDS layout: 128B paired-row lines (2 M-rows x 64B), 8x16B slots XOR-
// swizzled by (line&7) -> 0 measured bank conflicts. Stage side pre-swizzles
// the GLOBAL source address; LDS dest stays linear (gl2lds requirement).
// MODE 0: scatter bf16 to q/k ([B,NH,S,HD]) + V^T ([B,NH,HD,S'])
//         S' key-interleaved within 32-groups:
//         k' = (k&~31) | ((k>>2)&3)<<3 | ((k>>4)&1)<<2 | (k&3).
//         q PRE-SCALED by 0.125*log2(e) so attn exp2's the raw MFMA out.
// MODE 1: fp32 store outf[m*N+n].
// ---------------------------------------------------------------------------
template<int MODE, int BN>
__global__ __launch_bounds__(256)
void gemm_nt(const unsigned short* __restrict__ A,
             const unsigned short* __restrict__ Bm,
             unsigned short* __restrict__ out0,
             unsigned short* __restrict__ out1,
             unsigned short* __restrict__ out2,
             float* __restrict__ outf,
             int N)
{
    constexpr int BUFB  = 8192 + BN * 64;        // bytes per buffer (A + B)
    constexpr int NSTEP = 32;                    // K / 32
    constexpr int NA    = 2;                     // A DMAs per wave per stage
    constexpr int NB    = BN / 64;               // B DMAs per wave per stage
    constexpr int BSL   = BN / 32;
    __shared__ unsigned char smem[3 * BUFB];
    const int K = 1024;
    const int tid  = threadIdx.x;
    const int wave = tid >> 6, lane = tid & 63;
    const int l15  = lane & 15, quad = lane >> 4;
    const int wm = wave >> 1, wn = wave & 1;

    int Lid = blockIdx.y * gridDim.x + blockIdx.x;
    int bm = (Lid & 7) * 4 + ((Lid >> 3) & 3);
    int bn = Lid >> 5;

    floatx4 acc[4][BSL];
#pragma unroll
    for (int i = 0; i < 4; i++)
#pragma unroll
        for (int j = 0; j < BSL; j++)
            acc[i][j] = floatx4{0.f, 0.f, 0.f, 0.f};

    // staging maps: chunk s (16B units) -> LDS line L = s>>3, slot p = s&7.
    // content q = p ^ (L&7): global (Mrow = L*2 + (q>>2), Kblk = q&3).
    int soffA[NA], soffB[NB];
#pragma unroll
    for (int l = 0; l < NA; l++) {
        int s = (wave * NA + l) * 64 + lane;
        int L = s >> 3, q = (s & 7) ^ (L & 7);
        soffA[l] = (L * 2 + (q >> 2)) * K + (q & 3) * 8;
    }
#pragma unroll
    for (int l = 0; l < NB; l++) {
        int s = (wave * NB + l) * 64 + lane;
        int L = s >> 3, q = (s & 7) ^ (L & 7);
        soffB[l] = (L * 2 + (q >> 2)) * K + (q & 3) * 8;
    }
    // read maps: row r, K-block quad -> line r>>1, slot (((r&1)<<2)|quad)^(line&7)
    int aoff[4], boff[BSL];
#pragma unroll
    for (int i = 0; i < 4; i++) {
        int r = wm * 64 + i * 16 + l15, L = r >> 1;
        aoff[i] = L * 128 + (((((r & 1) << 2) | quad) ^ (L & 7)) * 16);
    }
#pragma unroll
    for (int j = 0; j < BSL; j++) {
        int r = wn * (BN / 2) + j * 16 + l15, L = r >> 1;
        boff[j] = 8192 + L * 128 + (((((r & 1) << 2) | quad) ^ (L & 7)) * 16);
    }

    const unsigned short* Abase = A  + (size_t)(bm * 128) * K;
    const unsigned short* Bbase = Bm + (size_t)(bn * BN) * K;

    auto STAGE = [&](int u, int bufb) {
        const int k0 = u * 32;
#pragma unroll
        for (int l = 0; l < NA; l++)
            gl2lds16(Abase + (size_t)soffA[l] + k0, &smem[bufb + (wave * NA + l) * 1024]);
#pragma unroll
        for (int l = 0; l < NB; l++)
            gl2lds16(Bbase + (size_t)soffB[l] + k0, &smem[bufb + 8192 + (wave * NB + l) * 1024]);
    };

    // prologue: stages 0,1 into buffers 0,1
    STAGE(0, 0);
    STAGE(1, BUFB);

    int b0 = 0, b2 = 2;                          // compute buf, stage buf
    for (int t = 0; t < NSTEP; t++) {
        // barrier 1: all waves done computing step t-1 -> buf[b2] reusable
        asm volatile("" ::: "memory");
        __builtin_amdgcn_s_barrier();
        asm volatile("" ::: "memory");
        if (t + 2 < NSTEP) {
            STAGE(t + 2, b2 * BUFB);
            // retire stage(t); stages t+1,t+2 (2*NDMA) stay in flight
            if (BN == 128) asm volatile("s_waitcnt vmcnt(8)" ::: "memory");
            else           asm volatile("s_waitcnt vmcnt(6)" ::: "memory");
        } else if (t + 2 == NSTEP) {
            if (BN == 128) asm volatile("s_waitcnt vmcnt(4)" ::: "memory");
            else           asm volatile("s_waitcnt vmcnt(3)" ::: "memory");
        } else {
            asm volatile("s_waitcnt vmcnt(0)" ::: "memory");
        }
        // barrier 2: tile t visible block-wide
        __builtin_amdgcn_s_barrier();
        asm volatile("" ::: "memory");

        const int cb = b0 * BUFB;
        short8 af[4], bfr[BSL];
#pragma unroll
        for (int i = 0; i < 4; i++)
            af[i] = *(const short8*)(&smem[cb + aoff[i]]);
#pragma unroll
        for (int j = 0; j < BSL; j++)
            bfr[j] = *(const short8*)(&smem[cb + boff[j]]);
#pragma unroll
        for (int i = 0; i < 4; i++)
#pragma unroll
            for (int j = 0; j < BSL; j++)
                acc[i][j] = MFMA32(af[i], bfr[j], acc[i][j]);

        b0 = (b0 == 2) ? 0 : b0 + 1;
        b2 = (b2 == 2) ? 0 : b2 + 1;
    }

#pragma unroll
    for (int i = 0; i < 4; i++) {
#pragma unroll
        for (int j = 0; j < BSL; j++) {
            int n = bn * BN + wn * (BN / 2) + j * 16 + l15;
#pragma unroll
            for (int r = 0; r < 4; r++) {
                int m = bm * 128 + wm * 64 + i * 16 + quad * 4 + r;
                float fv = acc[i][j][r];
                if (MODE == 1) {
                    outf[(size_t)m * N + n] = fv;
                } else {
                    int t = n >> 10;            // 0=q 1=k 2=v
                    int h = (n >> 6) & 15;
                    int d = n & 63;
                    int b = m >> 11, si = m & 2047;
                    if (t == 2) {
                        // V^T with key interleave within 32-groups
                        int sip = (si & ~31) | (((si >> 2) & 3) << 3)
                                | (((si >> 4) & 1) << 2) | (si & 3);
                        out2[(((size_t)(b * 16 + h)) * 64 + d) * 2048 + sip] = f2bf(fv);
                    } else {
                        // q pre-scaled by 0.125*log2(e) (softmax fold)
                        if (t == 0) fv *= 0.18033688f;
                        size_t off = (((size_t)(b * 16 + h)) * 2048 + si) * 64 + d;
                        unsigned short* dst = (t == 0) ? out0 : out1;
                        dst[off] = f2bf(fv);
                    }
                }
            }
        }
    }
}

// ---------------------------------------------------------------------------
// Flash attention v15 — KVBLK=64 on v12's verified topology (round-11 A/B):
//  * v14's regression isolated to its 128-thread block shape (occupancy
//    15%), NOT the KVBLK=64 idea. v15 keeps v12's topology: 256-thread /
//    4-wave blocks, 32 q-rows per wave (128 q/block), grid 512, 2 blk/CU —
//    so vs v12 the ONLY changes are sync granularity and per-region ILP:
//      barrier pairs 128 -> 64, MFMA per wave per region 18 -> 36,
//      16 batched ds_read_b128 per region.
//  * LDS 2 x (K 8KB + V 8KB) = 32KB. Both tiles: 64 x 128B rows with the
//    verified row-XOR slot swizzle (0 conflicts). Staging pre-swizzles the
//    GLOBAL source; LDS dest linear (gl2lds requirement).
//  * vmcnt ledger/wave (4 DMAs/stage, 4 mf loads): iter i: mf(4), barrier1,
//    stage(i+1)(4), vmcnt(4) [retires stage(i)+mf(i), keeps stage(i+1)],
//    barrier2, compute. Tail i=31: vmcnt(0).
//  * T5 setprio(1) around QK and PV MFMA clusters (carried from v14).
// Carried verified pieces: q-split wave-complete softmax (no cross-wave
// reduction), full-K=32 PV via key-interleaved V^T, mask addend in QK
// C-init, Q pre-scaled by 0.125*log2e -> exp2 on raw MFMA output.
// ---------------------------------------------------------------------------
__global__ __launch_bounds__(256, 2)
void attn_kernel(const unsigned short* __restrict__ Qb,
                 const unsigned short* __restrict__ Kb,
                 const unsigned short* __restrict__ VbT,
                 const float* __restrict__ m2b,
                 const float* __restrict__ gateb,
                 unsigned short* __restrict__ ctx)
{
    __shared__ unsigned char smem[32768];        // 2 x (K 8KB + V 8KB)
    const int S = 2048;
    const int tid  = threadIdx.x;
    const int wave = tid >> 6, lane = tid & 63;
    const int l15  = lane & 15, quad = lane >> 4;

    int Lid = blockIdx.y * gridDim.x + blockIdx.x;
    int bh = (Lid & 7) * 4 + ((Lid >> 3) & 3);   // [0,32)
    int qc = Lid >> 5;                           // [0,16): 128 q-rows/block
    const int b = bh >> 4, h = bh & 15;
    const int q0 = qc * 128 + wave * 32;         // this wave's 32 q-rows

    const size_t headoff = (size_t)bh * S * 64;
    const unsigned short* Qh  = Qb  + headoff;   // [S][64] (pre-scaled)
    const unsigned short* Kh  = Kb  + headoff;   // [S][64]
    const unsigned short* VhT = VbT + headoff;   // [64][S'] key-interleaved
    const float* m2p = m2b + (size_t)b * S;

    // staging maps (s = (wave*2+l)*64 + lane covers 512 16B-chunks of each
    // 8KB section): line L = s>>3 (K: key row / V: d row, both 128B),
    // slot p = s&7, content chunk c = p^(L&7).
    // K src: (kb+L)*64 + c*8 ; V src: L*2048 + kb + c*8.
    int koff[2], voff[2];
#pragma unroll
    for (int l = 0; l < 2; l++) {
        int s = (wave * 2 + l) * 64 + lane;
        int L = s >> 3, c = (s & 7) ^ (L & 7);
        koff[l] = L * 64 + c * 8;
        voff[l] = L * 2048 + c * 8;
    }
    // read map (shared by K and V: 128B rows, row-XOR slots — verified
    // 0-conflict): row r=l15 within a 16-row subtile, col-chunk j:
    // qkoff[j] = l15*128 + ((j*4+quad) ^ (l15&7))*16 ; add kt*2048 (K) or
    // 8192 + dt*2048 (V).
    int qkoff[2];
#pragma unroll
    for (int j = 0; j < 2; j++)
        qkoff[j] = l15 * 128 + (((j * 4 + quad) ^ (l15 & 7)) * 16);

    // Q B-frags: aq[sub][s2] = Q[q0+sub*16+l15][s2*32+quad*8+..]
    short8 aq[2][2];
#pragma unroll
    for (int sub = 0; sub < 2; sub++)
#pragma unroll
        for (int s2 = 0; s2 < 2; s2++)
            aq[sub][s2] = *(const short8*)(Qh + (size_t)(q0 + sub * 16 + l15) * 64 + s2 * 32 + quad * 8);

    floatx4 o[2][4];                 // O^T partial [sub][dt]
    floatx4 lq[2];                   // l partial [sub]
#pragma unroll
    for (int sub = 0; sub < 2; sub++) {
        lq[sub] = floatx4{0.f, 0.f, 0.f, 0.f};
#pragma unroll
        for (int dt = 0; dt < 4; dt++) o[sub][dt] = floatx4{0.f, 0.f, 0.f, 0.f};
    }

    const uint4v onesu = {0x3F803F80u, 0x3F803F80u, 0x3F803F80u, 0x3F803F80u};
    const short8 ONES = __builtin_bit_cast(short8, onesu);

    // prologue: stage chunk 0 (keys 0..63) into buffer 0
#pragma unroll
    for (int l = 0; l < 2; l++) {
        gl2lds16(Kh + koff[l], &smem[(wave * 2 + l) * 1024]);
        gl2lds16(VhT + voff[l], &smem[8192 + (wave * 2 + l) * 1024]);
    }

    for (int i = 0; i < 32; i++) {
        const int cb = (i & 1) * 16384;
        const int nb = ((i + 1) & 1) * 16384;
        const int kb = i * 64;
        // mask addends for the 4 key sub-tiles (QK C-init: row == quad*4+r)
        floatx4 mf[4];
#pragma unroll
        for (int t = 0; t < 4; t++)
            mf[t] = *(const floatx4*)(m2p + kb + t * 16 + quad * 4);
        asm volatile("" ::: "memory");
        // barrier 1: all waves done reading buf[nb] (iter i-1)
        __builtin_amdgcn_s_barrier();
        asm volatile("" ::: "memory");
        if (i + 1 < 32) {
            const int kbn = (i + 1) * 64;
#pragma unroll
            for (int l = 0; l < 2; l++) {
                gl2lds16(Kh + (size_t)kbn * 64 + koff[l], &smem[nb + (wave * 2 + l) * 1024]);
                gl2lds16(VhT + kbn + voff[l], &smem[nb + 8192 + (wave * 2 + l) * 1024]);
            }
            // retire stage(i)+mf(i); stage(i+1)'s 4 stay in flight
            asm volatile("s_waitcnt vmcnt(4)" ::: "memory");
        } else {
            asm volatile("s_waitcnt vmcnt(0)" ::: "memory");
        }
        // barrier 2: whole chunk i visible block-wide
        __builtin_amdgcn_s_barrier();
        asm volatile("" ::: "memory");

        // K frags (consumed by QK before vf loads -> bounded reg pressure)
        short8 kf[4][2];
#pragma unroll
        for (int kt = 0; kt < 4; kt++)
#pragma unroll
            for (int s2 = 0; s2 < 2; s2++)
                kf[kt][s2] = *(const short8*)(&smem[cb + kt * 2048 + qkoff[s2]]);

        // QK for both subs: st[sub][kt], C init = mask addend
        floatx4 st[2][4];
        __builtin_amdgcn_s_setprio(1);
#pragma unroll
        for (int sub = 0; sub < 2; sub++)
#pragma unroll
            for (int kt = 0; kt < 4; kt++) {
                st[sub][kt] = MFMA32(kf[kt][0], aq[sub][0], mf[kt]);
                st[sub][kt] = MFMA32(kf[kt][1], aq[sub][1], st[sub][kt]);
            }
        __builtin_amdgcn_s_setprio(0);

        // V frags (128B-row swizzle, interleaved key positions)
        short8 vf[4][2];
#pragma unroll
        for (int dt = 0; dt < 4; dt++)
#pragma unroll
            for (int g = 0; g < 2; g++)
                vf[dt][g] = *(const short8*)(&smem[cb + 8192 + dt * 2048 + qkoff[g]]);

        // exp + pack (Q pre-scaled, mask in C-init): pf[sub][g] covers the
        // 32-key group g in interleave order {t0 e0..e3, t1 e0..e3}
        short8 pf[2][2];
#pragma unroll
        for (int sub = 0; sub < 2; sub++)
#pragma unroll
            for (int g = 0; g < 2; g++) {
                floatx4 a = st[sub][2 * g], c = st[sub][2 * g + 1];
                uint4v pu = {pack_bf2(EXP2(a[0]), EXP2(a[1])),
                             pack_bf2(EXP2(a[2]), EXP2(a[3])),
                             pack_bf2(EXP2(c[0]), EXP2(c[1])),
                             pack_bf2(EXP2(c[2]), EXP2(c[3]))};
                pf[sub][g] = __builtin_bit_cast(short8, pu);
            }

        // PV + l: full-K=32 per group, un-padded
        __builtin_amdgcn_s_setprio(1);
#pragma unroll
        for (int sub = 0; sub < 2; sub++)
#pragma unroll
            for (int g = 0; g < 2; g++) {
#pragma unroll
                for (int dt = 0; dt < 4; dt++)
                    o[sub][dt] = MFMA32(vf[dt][g], pf[sub][g], o[sub][dt]);
                lq[sub] = MFMA32(ONES, pf[sub][g], lq[sub]);
            }
        __builtin_amdgcn_s_setprio(0);
    }

    // epilogue: wave-complete softmax; lane writes q = q0+sub*16+l15, all dt
    float g = gateb[h];
#pragma unroll
    for (int sub = 0; sub < 2; sub++) {
        float iv = g / lq[sub][0];
        size_t base = ((size_t)(b * 2048 + q0 + sub * 16 + l15)) * 1024 + h * 64 + quad * 4;
#pragma unroll
        for (int dt = 0; dt < 4; dt++) {
            uint2v w;
            w[0] = pack_bf2(o[sub][dt][0] * iv, o[sub][dt][1] * iv);
            w[1] = pack_bf2(o[sub][dt][2] * iv, o[sub][dt][3] * iv);
            *(uint2v*)(ctx + base + dt * 16) = w;
        }
    }
}

// ---------------------------------------------------------------------------
extern "C" void kernel_launch(void* const* d_in, const int* in_sizes, int n_in,
                              void* d_out, int out_size, void* d_ws, size_t ws_size,
                              hipStream_t stream)
{
    const float* hidden = (const float*)d_in[0]; // [2,2048,1024] fp32
    const float* mask   = (const float*)d_in[1]; // [2,1,1,2048]  fp32
    const float* w_qkv  = (const float*)d_in[2]; // [3072,1024]   fp32
    const float* w_out  = (const float*)d_in[3]; // [1024,1024]   fp32
    const float* gate   = (const float*)d_in[4]; // [16]          fp32
    float* out = (float*)d_out;                  // [2,2048,1024] fp32

    unsigned short* q_buf = (unsigned short*)d_ws;   // [2,16,2048,64] bf16 (pre-scaled)
    unsigned short* k_buf = q_buf + 4194304;         // [2,16,2048,64]
    unsigned short* v_buf = k_buf + 4194304;         // [2,16,64,2048] (V^T, interleaved)
    unsigned short* c_buf = v_buf + 4194304;         // [2,2048,1024]  bf16
    unsigned short* h_bf  = c_buf + 4194304;         // hidden bf16
    unsigned short* wq_bf = h_bf  + 4194304;         // w_qkv bf16
    unsigned short* wo_bf = wq_bf + 3145728;         // w_out bf16
    float* m2_buf = (float*)(wo_bf + 1048576);       // [2,2048] fp32

    // one-pass prep: fp32->bf16 converts + mask transform
    cvt_all<<<8196, 256, 0, stream>>>(hidden, w_qkv, w_out, mask,
                                      h_bf, wq_bf, wo_bf, m2_buf);

    // QKV projection, scatter q(pre-scaled)/k/V^T(interleaved)
    gemm_nt<0, 128><<<dim3(24, 32), 256, 0, stream>>>(h_bf, wq_bf, q_buf, k_buf, v_buf, nullptr, 3072);
    // fused flash attention + gate -> ctx bf16 (128-q blocks of 4 waves, grid 512)
    attn_kernel<<<dim3(16, 32), 256, 0, stream>>>(q_buf, k_buf, v_buf, m2_buf, gate, c_buf);
    // output projection -> out fp32 (grid 16x32, 128x64 tiles)
    gemm_nt<1, 64><<<dim3(16, 32), 256, 0, stream>>>(c_buf, wo_bf, nullptr, nullptr, nullptr, out, 1024);
}

// Round 13
// 179.438 us; speedup vs baseline: 1.0825x; 1.0178x over previous
//
#include <hip/hip_runtime.h>
#include <stdint.h>

// Problem constants: B=2, S=2048, H=1024, NH=16, HD=64, K=1024
// Inputs FP32 -> one cvt pass to bf16 -> bf16 MFMA pipeline -> output FP32.

typedef __attribute__((ext_vector_type(8))) short short8;
typedef __attribute__((ext_vector_type(4))) float floatx4;
typedef __attribute__((ext_vector_type(4))) unsigned int uint4v;
typedef __attribute__((ext_vector_type(2))) unsigned int uint2v;

__device__ __forceinline__ unsigned short f2bf(float f) {          // RNE
    unsigned int u = __float_as_uint(f);
    unsigned int r = u + 0x7fffu + ((u >> 16) & 1u);
    return (unsigned short)(r >> 16);
}
// pack two fp32 -> bf16x2 dword
#if __has_builtin(__builtin_amdgcn_cvt_pk_bf16_f32)
__device__ __forceinline__ unsigned int pack_bf2(float lo, float hi) {
    auto v = __builtin_amdgcn_cvt_pk_bf16_f32(lo, hi);
    return __builtin_bit_cast(unsigned int, v);
}
#else
__device__ __forceinline__ unsigned int pack_bf2(float lo, float hi) {
    unsigned int a = __float_as_uint(lo) + 0x8000u;
    unsigned int b = __float_as_uint(hi) + 0x8000u;
    return __builtin_amdgcn_perm(b, a, 0x07060302u);
}
#endif

// raw exp2 (v_exp_f32) when available
#if __has_builtin(__builtin_amdgcn_exp2f)
#define EXP2(x) __builtin_amdgcn_exp2f(x)
#else
#define EXP2(x) exp2f(x)
#endif

// async global->LDS, 16B per lane. LDS dest: wave-uniform base + lane*16.
__device__ __forceinline__ void gl2lds16(const void* g, void* l) {
    __builtin_amdgcn_global_load_lds(
        (const __attribute__((address_space(1))) unsigned int*)g,
        (__attribute__((address_space(3))) unsigned int*)l, 16, 0, 0);
}

#define MFMA32(a, b, c) __builtin_amdgcn_mfma_f32_16x16x32_bf16((a), (b), (c), 0, 0, 0)

// ---------------------------------------------------------------------------
// One-pass prep: fp32->bf16 for hidden / w_qkv / w_out, plus mask transform
// m2 = mask*log2(e) - 10*log2(e) (fp32). Grid exactly 8196 x 256.
// ---------------------------------------------------------------------------
__global__ __launch_bounds__(256)
void cvt_all(const float* __restrict__ a, const float* __restrict__ b,
             const float* __restrict__ c, const float* __restrict__ mask,
             unsigned short* __restrict__ oa, unsigned short* __restrict__ ob,
             unsigned short* __restrict__ oc, float* __restrict__ m2b)
{
    int i = blockIdx.x * 256 + threadIdx.x;
    if (i >= 2097152) {                     // mask range: 1024 groups
        int off = i - 2097152;
        float4 v = *(const float4*)(mask + (size_t)off * 4);
        const float L2E = 1.44269504f, C2 = -14.4269504f;
        float4 w;
        w.x = fmaf(v.x, L2E, C2); w.y = fmaf(v.y, L2E, C2);
        w.z = fmaf(v.z, L2E, C2); w.w = fmaf(v.w, L2E, C2);
        *(float4*)(m2b + (size_t)off * 4) = w;
        return;
    }
    const float* src; unsigned short* dst; int off;
    if (i < 1048576)      { src = a; dst = oa; off = i; }
    else if (i < 1835008) { src = b; dst = ob; off = i - 1048576; }
    else                  { src = c; dst = oc; off = i - 1835008; }
    float4 v = *(const float4*)(src + (size_t)off * 4);
    uint2v w;
    w[0] = pack_bf2(v.x, v.y);
    w[1] = pack_bf2(v.z, v.w);
    *(uint2v*)(dst + (size_t)off * 4) = w;
}

// ---------------------------------------------------------------------------
// NT GEMM v4: QUAD-buffered LDS + SINGLE barrier per step (round-12 A/B).
// 128 x BN tile, BK=32, 4 waves (2x2) x (64 x BN/2), depth-2 prefetch.
// Round-11 PMC: with tri-buffer + 2 barriers the step time was ~3600cy vs
// a ~760cy issue budget, and occupancy read anomalously low — the per-step
// barrier pair is the suspected stall. With FOUR buffers, stage(t+2)
// targets buf[(t-2)&3] whose last reader was compute(t-2); the step-(t-1)
// barrier already proves every wave is past compute(t-2), so the
// write-protect barrier is PROVABLY redundant: stage -> vmcnt -> barrier
// (visibility only) -> compute. Barriers/loop: 64 -> 32. vmcnt ledger
// unchanged (steady vmcnt(2*NDMA), tail NDMA, 0).
// LDS: MODE0 4x16KB=64KB, MODE1 4x12KB=48KB.
// LDS layout (verified 0-conflict): 128B paired-row lines (2 M-rows x 64B),
// 8x16B slots XOR-swizzled by (line&7). Stage side pre-swizzles the GLOBAL
// source address; LDS dest stays linear (gl2lds requirement).
// MODE 0: scatter bf16 to q/k ([B,NH,S,HD]) + V^T ([B,NH,HD,S'])
//         S' key-interleaved within 32-groups:
//         k' = (k&~31) | ((k>>2)&3)<<3 | ((k>>4)&1)<<2 | (k&3).
//         q PRE-SCALED by 0.125*log2(e) so attn exp2's the raw MFMA out.
// MODE 1: fp32 store outf[m*N+n].
// ---------------------------------------------------------------------------
template<int MODE, int BN>
__global__ __launch_bounds__(256)
void gemm_nt(const unsigned short* __restrict__ A,
             const unsigned short* __restrict__ Bm,
             unsigned short* __restrict__ out0,
             unsigned short* __restrict__ out1,
             unsigned short* __restrict__ out2,
             float* __restrict__ outf,
             int N)
{
    constexpr int BUFB  = 8192 + BN * 64;        // bytes per buffer (A + B)
    constexpr int NSTEP = 32;                    // K / 32
    constexpr int NA    = 2;                     // A DMAs per wave per stage
    constexpr int NB    = BN / 64;               // B DMAs per wave per stage
    constexpr int BSL   = BN / 32;
    __shared__ unsigned char smem[4 * BUFB];
    const int K = 1024;
    const int tid  = threadIdx.x;
    const int wave = tid >> 6, lane = tid & 63;
    const int l15  = lane & 15, quad = lane >> 4;
    const int wm = wave >> 1, wn = wave & 1;

    int Lid = blockIdx.y * gridDim.x + blockIdx.x;
    int bm = (Lid & 7) * 4 + ((Lid >> 3) & 3);
    int bn = Lid >> 5;

    floatx4 acc[4][BSL];
#pragma unroll
    for (int i = 0; i < 4; i++)
#pragma unroll
        for (int j = 0; j < BSL; j++)
            acc[i][j] = floatx4{0.f, 0.f, 0.f, 0.f};

    // staging maps: chunk s (16B units) -> LDS line L = s>>3, slot p = s&7.
    // content q = p ^ (L&7): global (Mrow = L*2 + (q>>2), Kblk = q&3).
    int soffA[NA], soffB[NB];
#pragma unroll
    for (int l = 0; l < NA; l++) {
        int s = (wave * NA + l) * 64 + lane;
        int L = s >> 3, q = (s & 7) ^ (L & 7);
        soffA[l] = (L * 2 + (q >> 2)) * K + (q & 3) * 8;
    }
#pragma unroll
    for (int l = 0; l < NB; l++) {
        int s = (wave * NB + l) * 64 + lane;
        int L = s >> 3, q = (s & 7) ^ (L & 7);
        soffB[l] = (L * 2 + (q >> 2)) * K + (q & 3) * 8;
    }
    // read maps: row r, K-block quad -> line r>>1, slot (((r&1)<<2)|quad)^(line&7)
    int aoff[4], boff[BSL];
#pragma unroll
    for (int i = 0; i < 4; i++) {
        int r = wm * 64 + i * 16 + l15, L = r >> 1;
        aoff[i] = L * 128 + (((((r & 1) << 2) | quad) ^ (L & 7)) * 16);
    }
#pragma unroll
    for (int j = 0; j < BSL; j++) {
        int r = wn * (BN / 2) + j * 16 + l15, L = r >> 1;
        boff[j] = 8192 + L * 128 + (((((r & 1) << 2) | quad) ^ (L & 7)) * 16);
    }

    const unsigned short* Abase = A  + (size_t)(bm * 128) * K;
    const unsigned short* Bbase = Bm + (size_t)(bn * BN) * K;

    auto STAGE = [&](int u, int bufb) {
        const int k0 = u * 32;
#pragma unroll
        for (int l = 0; l < NA; l++)
            gl2lds16(Abase + (size_t)soffA[l] + k0, &smem[bufb + (wave * NA + l) * 1024]);
#pragma unroll
        for (int l = 0; l < NB; l++)
            gl2lds16(Bbase + (size_t)soffB[l] + k0, &smem[bufb + 8192 + (wave * NB + l) * 1024]);
    };

    // prologue: stages 0,1 into buffers 0,1
    STAGE(0, 0);
    STAGE(1, BUFB);

    for (int t = 0; t < NSTEP; t++) {
        // stage(t+2) into buf[(t+2)&3]: last read at compute(t-2); the
        // step-(t-1) barrier already proved all waves are past compute(t-2)
        // -> no write-protect barrier needed (quad-buffer invariant).
        if (t + 2 < NSTEP) {
            STAGE(t + 2, ((t + 2) & 3) * BUFB);
            // retire stage(t); stages t+1,t+2 (2*NDMA) stay in flight
            if (BN == 128) asm volatile("s_waitcnt vmcnt(8)" ::: "memory");
            else           asm volatile("s_waitcnt vmcnt(6)" ::: "memory");
        } else if (t + 2 == NSTEP) {
            if (BN == 128) asm volatile("s_waitcnt vmcnt(4)" ::: "memory");
            else           asm volatile("s_waitcnt vmcnt(3)" ::: "memory");
        } else {
            asm volatile("s_waitcnt vmcnt(0)" ::: "memory");
        }
        // single barrier: tile t visible block-wide (each wave waited for
        // its own stage(t) portion above)
        __builtin_amdgcn_s_barrier();
        asm volatile("" ::: "memory");

        const int cb = (t & 3) * BUFB;
        short8 af[4], bfr[BSL];
#pragma unroll
        for (int i = 0; i < 4; i++)
            af[i] = *(const short8*)(&smem[cb + aoff[i]]);
#pragma unroll
        for (int j = 0; j < BSL; j++)
            bfr[j] = *(const short8*)(&smem[cb + boff[j]]);
#pragma unroll
        for (int i = 0; i < 4; i++)
#pragma unroll
            for (int j = 0; j < BSL; j++)
                acc[i][j] = MFMA32(af[i], bfr[j], acc[i][j]);
    }

#pragma unroll
    for (int i = 0; i < 4; i++) {
#pragma unroll
        for (int j = 0; j < BSL; j++) {
            int n = bn * BN + wn * (BN / 2) + j * 16 + l15;
#pragma unroll
            for (int r = 0; r < 4; r++) {
                int m = bm * 128 + wm * 64 + i * 16 + quad * 4 + r;
                float fv = acc[i][j][r];
                if (MODE == 1) {
                    outf[(size_t)m * N + n] = fv;
                } else {
                    int t = n >> 10;            // 0=q 1=k 2=v
                    int h = (n >> 6) & 15;
                    int d = n & 63;
                    int b = m >> 11, si = m & 2047;
                    if (t == 2) {
                        // V^T with key interleave within 32-groups
                        int sip = (si & ~31) | (((si >> 2) & 3) << 3)
                                | (((si >> 4) & 1) << 2) | (si & 3);
                        out2[(((size_t)(b * 16 + h)) * 64 + d) * 2048 + sip] = f2bf(fv);
                    } else {
                        // q pre-scaled by 0.125*log2(e) (softmax fold)
                        if (t == 0) fv *= 0.18033688f;
                        size_t off = (((size_t)(b * 16 + h)) * 2048 + si) * 64 + d;
                        unsigned short* dst = (t == 0) ? out0 : out1;
                        dst[off] = f2bf(fv);
                    }
                }
            }
        }
    }
}

// ---------------------------------------------------------------------------
// Flash attention v15 (verified round 12: attn left the top-5, was 50.3us):
// KVBLK=64 on the v12 topology — 256-thread / 4-wave blocks, 32 q-rows per
// wave (128 q/block), grid 512, 2 blk/CU; barrier pairs 64/loop, 36 MFMA
// per wave per region, 16 batched ds_read_b128 per region.
// LDS 2 x (K 8KB + V 8KB) = 32KB; both tiles 64 x 128B rows with the
// verified row-XOR slot swizzle (0 conflicts). Staging pre-swizzles the
// GLOBAL source; LDS dest linear (gl2lds requirement).
// vmcnt ledger/wave (4 DMAs/stage, 4 mf loads): iter i: mf(4), barrier1,
// stage(i+1)(4), vmcnt(4) [retires stage(i)+mf(i), keeps stage(i+1)],
// barrier2, compute. Tail i=31: vmcnt(0). T5 setprio around MFMA clusters.
// q-split wave-complete softmax, full-K=32 PV via key-interleaved V^T,
// mask addend in QK C-init, Q pre-scaled by 0.125*log2e -> exp2 raw.
// ---------------------------------------------------------------------------
__global__ __launch_bounds__(256, 2)
void attn_kernel(const unsigned short* __restrict__ Qb,
                 const unsigned short* __restrict__ Kb,
                 const unsigned short* __restrict__ VbT,
                 const float* __restrict__ m2b,
                 const float* __restrict__ gateb,
                 unsigned short* __restrict__ ctx)
{
    __shared__ unsigned char smem[32768];        // 2 x (K 8KB + V 8KB)
    const int S = 2048;
    const int tid  = threadIdx.x;
    const int wave = tid >> 6, lane = tid & 63;
    const int l15  = lane & 15, quad = lane >> 4;

    int Lid = blockIdx.y * gridDim.x + blockIdx.x;
    int bh = (Lid & 7) * 4 + ((Lid >> 3) & 3);   // [0,32)
    int qc = Lid >> 5;                           // [0,16): 128 q-rows/block
    const int b = bh >> 4, h = bh & 15;
    const int q0 = qc * 128 + wave * 32;         // this wave's 32 q-rows

    const size_t headoff = (size_t)bh * S * 64;
    const unsigned short* Qh  = Qb  + headoff;   // [S][64] (pre-scaled)
    const unsigned short* Kh  = Kb  + headoff;   // [S][64]
    const unsigned short* VhT = VbT + headoff;   // [64][S'] key-interleaved
    const float* m2p = m2b + (size_t)b * S;

    // staging maps (s = (wave*2+l)*64 + lane covers 512 16B-chunks of each
    // 8KB section): line L = s>>3 (K: key row / V: d row, both 128B),
    // slot p = s&7, content chunk c = p^(L&7).
    // K src: (kb+L)*64 + c*8 ; V src: L*2048 + kb + c*8.
    int koff[2], voff[2];
#pragma unroll
    for (int l = 0; l < 2; l++) {
        int s = (wave * 2 + l) * 64 + lane;
        int L = s >> 3, c = (s & 7) ^ (L & 7);
        koff[l] = L * 64 + c * 8;
        voff[l] = L * 2048 + c * 8;
    }
    // read map (shared by K and V: 128B rows, row-XOR slots — verified
    // 0-conflict): row r=l15 within a 16-row subtile, col-chunk j:
    // qkoff[j] = l15*128 + ((j*4+quad) ^ (l15&7))*16 ; add kt*2048 (K) or
    // 8192 + dt*2048 (V).
    int qkoff[2];
#pragma unroll
    for (int j = 0; j < 2; j++)
        qkoff[j] = l15 * 128 + (((j * 4 + quad) ^ (l15 & 7)) * 16);

    // Q B-frags: aq[sub][s2] = Q[q0+sub*16+l15][s2*32+quad*8+..]
    short8 aq[2][2];
#pragma unroll
    for (int sub = 0; sub < 2; sub++)
#pragma unroll
        for (int s2 = 0; s2 < 2; s2++)
            aq[sub][s2] = *(const short8*)(Qh + (size_t)(q0 + sub * 16 + l15) * 64 + s2 * 32 + quad * 8);

    floatx4 o[2][4];                 // O^T partial [sub][dt]
    floatx4 lq[2];                   // l partial [sub]
#pragma unroll
    for (int sub = 0; sub < 2; sub++) {
        lq[sub] = floatx4{0.f, 0.f, 0.f, 0.f};
#pragma unroll
        for (int dt = 0; dt < 4; dt++) o[sub][dt] = floatx4{0.f, 0.f, 0.f, 0.f};
    }

    const uint4v onesu = {0x3F803F80u, 0x3F803F80u, 0x3F803F80u, 0x3F803F80u};
    const short8 ONES = __builtin_bit_cast(short8, onesu);

    // prologue: stage chunk 0 (keys 0..63) into buffer 0
#pragma unroll
    for (int l = 0; l < 2; l++) {
        gl2lds16(Kh + koff[l], &smem[(wave * 2 + l) * 1024]);
        gl2lds16(VhT + voff[l], &smem[8192 + (wave * 2 + l) * 1024]);
    }

    for (int i = 0; i < 32; i++) {
        const int cb = (i & 1) * 16384;
        const int nb = ((i + 1) & 1) * 16384;
        const int kb = i * 64;
        // mask addends for the 4 key sub-tiles (QK C-init: row == quad*4+r)
        floatx4 mf[4];
#pragma unroll
        for (int t = 0; t < 4; t++)
            mf[t] = *(const floatx4*)(m2p + kb + t * 16 + quad * 4);
        asm volatile("" ::: "memory");
        // barrier 1: all waves done reading buf[nb] (iter i-1)
        __builtin_amdgcn_s_barrier();
        asm volatile("" ::: "memory");
        if (i + 1 < 32) {
            const int kbn = (i + 1) * 64;
#pragma unroll
            for (int l = 0; l < 2; l++) {
                gl2lds16(Kh + (size_t)kbn * 64 + koff[l], &smem[nb + (wave * 2 + l) * 1024]);
                gl2lds16(VhT + kbn + voff[l], &smem[nb + 8192 + (wave * 2 + l) * 1024]);
            }
            // retire stage(i)+mf(i); stage(i+1)'s 4 stay in flight
            asm volatile("s_waitcnt vmcnt(4)" ::: "memory");
        } else {
            asm volatile("s_waitcnt vmcnt(0)" ::: "memory");
        }
        // barrier 2: whole chunk i visible block-wide
        __builtin_amdgcn_s_barrier();
        asm volatile("" ::: "memory");

        // K frags (consumed by QK before vf loads -> bounded reg pressure)
        short8 kf[4][2];
#pragma unroll
        for (int kt = 0; kt < 4; kt++)
#pragma unroll
            for (int s2 = 0; s2 < 2; s2++)
                kf[kt][s2] = *(const short8*)(&smem[cb + kt * 2048 + qkoff[s2]]);

        // QK for both subs: st[sub][kt], C init = mask addend
        floatx4 st[2][4];
        __builtin_amdgcn_s_setprio(1);
#pragma unroll
        for (int sub = 0; sub < 2; sub++)
#pragma unroll
            for (int kt = 0; kt < 4; kt++) {
                st[sub][kt] = MFMA32(kf[kt][0], aq[sub][0], mf[kt]);
                st[sub][kt] = MFMA32(kf[kt][1], aq[sub][1], st[sub][kt]);
            }
        __builtin_amdgcn_s_setprio(0);

        // V frags (128B-row swizzle, interleaved key positions)
        short8 vf[4][2];
#pragma unroll
        for (int dt = 0; dt < 4; dt++)
#pragma unroll
            for (int g = 0; g < 2; g++)
                vf[dt][g] = *(const short8*)(&smem[cb + 8192 + dt * 2048 + qkoff[g]]);

        // exp + pack (Q pre-scaled, mask in C-init): pf[sub][g] covers the
        // 32-key group g in interleave order {t0 e0..e3, t1 e0..e3}
        short8 pf[2][2];
#pragma unroll
        for (int sub = 0; sub < 2; sub++)
#pragma unroll
            for (int g = 0; g < 2; g++) {
                floatx4 a = st[sub][2 * g], c = st[sub][2 * g + 1];
                uint4v pu = {pack_bf2(EXP2(a[0]), EXP2(a[1])),
                             pack_bf2(EXP2(a[2]), EXP2(a[3])),
                             pack_bf2(EXP2(c[0]), EXP2(c[1])),
                             pack_bf2(EXP2(c[2]), EXP2(c[3]))};
                pf[sub][g] = __builtin_bit_cast(short8, pu);
            }

        // PV + l: full-K=32 per group, un-padded
        __builtin_amdgcn_s_setprio(1);
#pragma unroll
        for (int sub = 0; sub < 2; sub++)
#pragma unroll
            for (int g = 0; g < 2; g++) {
#pragma unroll
                for (int dt = 0; dt < 4; dt++)
                    o[sub][dt] = MFMA32(vf[dt][g], pf[sub][g], o[sub][dt]);
                lq[sub] = MFMA32(ONES, pf[sub][g], lq[sub]);
            }
        __builtin_amdgcn_s_setprio(0);
    }

    // epilogue: wave-complete softmax; lane writes q = q0+sub*16+l15, all dt
    float g = gateb[h];
#pragma unroll
    for (int sub = 0; sub < 2; sub++) {
        float iv = g / lq[sub][0];
        size_t base = ((size_t)(b * 2048 + q0 + sub * 16 + l15)) * 1024 + h * 64 + quad * 4;
#pragma unroll
        for (int dt = 0; dt < 4; dt++) {
            uint2v w;
            w[0] = pack_bf2(o[sub][dt][0] * iv, o[sub][dt][1] * iv);
            w[1] = pack_bf2(o[sub][dt][2] * iv, o[sub][dt][3] * iv);
            *(uint2v*)(ctx + base + dt * 16) = w;
        }
    }
}

// ---------------------------------------------------------------------------
extern "C" void kernel_launch(void* const* d_in, const int* in_sizes, int n_in,
                              void* d_out, int out_size, void* d_ws, size_t ws_size,
                              hipStream_t stream)
{
    const float* hidden = (const float*)d_in[0]; // [2,2048,1024] fp32
    const float* mask   = (const float*)d_in[1]; // [2,1,1,2048]  fp32
    const float* w_qkv  = (const float*)d_in[2]; // [3072,1024]   fp32
    const float* w_out  = (const float*)d_in[3]; // [1024,1024]   fp32
    const float* gate   = (const float*)d_in[4]; // [16]          fp32
    float* out = (float*)d_out;                  // [2,2048,1024] fp32

    unsigned short* q_buf = (unsigned short*)d_ws;   // [2,16,2048,64] bf16 (pre-scaled)
    unsigned short* k_buf = q_buf + 4194304;         // [2,16,2048,64]
    unsigned short* v_buf = k_buf + 4194304;         // [2,16,64,2048] (V^T, interleaved)
    unsigned short* c_buf = v_buf + 4194304;         // [2,2048,1024]  bf16
    unsigned short* h_bf  = c_buf + 4194304;         // hidden bf16
    unsigned short* wq_bf = h_bf  + 4194304;         // w_qkv bf16
    unsigned short* wo_bf = wq_bf + 3145728;         // w_out bf16
    float* m2_buf = (float*)(wo_bf + 1048576);       // [2,2048] fp32

    // one-pass prep: fp32->bf16 converts + mask transform
    cvt_all<<<8196, 256, 0, stream>>>(hidden, w_qkv, w_out, mask,
                                      h_bf, wq_bf, wo_bf, m2_buf);

    // QKV projection, scatter q(pre-scaled)/k/V^T(interleaved)
    gemm_nt<0, 128><<<dim3(24, 32), 256, 0, stream>>>(h_bf, wq_bf, q_buf, k_buf, v_buf, nullptr, 3072);
    // fused flash attention + gate -> ctx bf16 (128-q blocks of 4 waves, grid 512)
    attn_kernel<<<dim3(16, 32), 256, 0, stream>>>(q_buf, k_buf, v_buf, m2_buf, gate, c_buf);
    // output projection -> out fp32 (grid 16x32, 128x64 tiles)
    gemm_nt<1, 64><<<dim3(16, 32), 256, 0, stream>>>(c_buf, wo_bf, nullptr, nullptr, nullptr, out, 1024);
}

// Round 14
// 177.391 us; speedup vs baseline: 1.0950x; 1.0115x over previous
//
#include <hip/hip_runtime.h>
#include <stdint.h>

// Problem constants: B=2, S=2048, H=1024, NH=16, HD=64, K=1024
// Inputs FP32 -> one cvt pass to bf16 -> bf16 MFMA pipeline -> output FP32.

typedef __attribute__((ext_vector_type(8))) short short8;
typedef __attribute__((ext_vector_type(4))) float floatx4;
typedef __attribute__((ext_vector_type(4))) unsigned int uint4v;
typedef __attribute__((ext_vector_type(2))) unsigned int uint2v;

__device__ __forceinline__ unsigned short f2bf(float f) {          // RNE
    unsigned int u = __float_as_uint(f);
    unsigned int r = u + 0x7fffu + ((u >> 16) & 1u);
    return (unsigned short)(r >> 16);
}
// pack two fp32 -> bf16x2 dword
#if __has_builtin(__builtin_amdgcn_cvt_pk_bf16_f32)
__device__ __forceinline__ unsigned int pack_bf2(float lo, float hi) {
    auto v = __builtin_amdgcn_cvt_pk_bf16_f32(lo, hi);
    return __builtin_bit_cast(unsigned int, v);
}
#else
__device__ __forceinline__ unsigned int pack_bf2(float lo, float hi) {
    unsigned int a = __float_as_uint(lo) + 0x8000u;
    unsigned int b = __float_as_uint(hi) + 0x8000u;
    return __builtin_amdgcn_perm(b, a, 0x07060302u);
}
#endif

// raw exp2 (v_exp_f32) when available
#if __has_builtin(__builtin_amdgcn_exp2f)
#define EXP2(x) __builtin_amdgcn_exp2f(x)
#else
#define EXP2(x) exp2f(x)
#endif

// async global->LDS, 16B per lane. LDS dest: wave-uniform base + lane*16.
__device__ __forceinline__ void gl2lds16(const void* g, void* l) {
    __builtin_amdgcn_global_load_lds(
        (const __attribute__((address_space(1))) unsigned int*)g,
        (__attribute__((address_space(3))) unsigned int*)l, 16, 0, 0);
}

#define MFMA32(a, b, c) __builtin_amdgcn_mfma_f32_16x16x32_bf16((a), (b), (c), 0, 0, 0)

// ---------------------------------------------------------------------------
// One-pass prep: fp32->bf16 for hidden / w_qkv / w_out, plus mask transform
// m2 = mask*log2(e) - 10*log2(e) (fp32). Grid exactly 8196 x 256.
// ---------------------------------------------------------------------------
__global__ __launch_bounds__(256)
void cvt_all(const float* __restrict__ a, const float* __restrict__ b,
             const float* __restrict__ c, const float* __restrict__ mask,
             unsigned short* __restrict__ oa, unsigned short* __restrict__ ob,
             unsigned short* __restrict__ oc, float* __restrict__ m2b)
{
    int i = blockIdx.x * 256 + threadIdx.x;
    if (i >= 2097152) {                     // mask range: 1024 groups
        int off = i - 2097152;
        float4 v = *(const float4*)(mask + (size_t)off * 4);
        const float L2E = 1.44269504f, C2 = -14.4269504f;
        float4 w;
        w.x = fmaf(v.x, L2E, C2); w.y = fmaf(v.y, L2E, C2);
        w.z = fmaf(v.z, L2E, C2); w.w = fmaf(v.w, L2E, C2);
        *(float4*)(m2b + (size_t)off * 4) = w;
        return;
    }
    const float* src; unsigned short* dst; int off;
    if (i < 1048576)      { src = a; dst = oa; off = i; }
    else if (i < 1835008) { src = b; dst = ob; off = i - 1048576; }
    else                  { src = c; dst = oc; off = i - 1835008; }
    float4 v = *(const float4*)(src + (size_t)off * 4);
    uint2v w;
    w[0] = pack_bf2(v.x, v.y);
    w[1] = pack_bf2(v.z, v.w);
    *(uint2v*)(dst + (size_t)off * 4) = w;
}

// ---------------------------------------------------------------------------
// NT GEMM v5: WAVES-parametrized 128 x BN tile, BK=32, tri-buffered LDS +
// depth-2 prefetch + counted vmcnt (round-8 verified scheme).
// Round-13 A/B: quad-buffer/1-barrier == tri/2-barrier (48us) -> sync
// structure exonerated. The untouched axis is wave TLP: 4-wave blocks give
// only 12 waves/CU for a serial per-step chain. v5 MODE0 uses EIGHT waves
// (512 threads) on the same tile: per-wave slice halves (acc[2][4], 8 MFMA
// + 6 ds_read/step, ~90 VGPR), 48KB LDS -> 3 blocks/CU = 24 waves/CU =
// 6 waves/SIMD — 2x the latency-hiding streams at identical total work.
// MODE1 keeps the verified 4-wave path (4KB B-tile can't feed 8 stage waves).
//   WAVES/2 row-groups x 2 col-groups; MI = 16/WAVES rows-subtiles;
//   NA = 8/WAVES, NB = BN/(16*WAVES) DMAs per wave per stage.
//   vmcnt ledger: steady 2*(NA+NB), tail NA+NB, then 0.
// LDS layout (verified 0-conflict): 128B paired-row lines (2 M-rows x 64B),
// 8x16B slots XOR-swizzled by (line&7). Stage side pre-swizzles the GLOBAL
// source address; LDS dest stays linear (gl2lds requirement).
// MODE 0: scatter bf16 to q/k ([B,NH,S,HD]) + V^T ([B,NH,HD,S'])
//         S' key-interleaved within 32-groups:
//         k' = (k&~31) | ((k>>2)&3)<<3 | ((k>>4)&1)<<2 | (k&3).
//         q PRE-SCALED by 0.125*log2(e) so attn exp2's the raw MFMA out.
// MODE 1: fp32 store outf[m*N+n].
// ---------------------------------------------------------------------------
template<int MODE, int BN, int WAVES>
__global__ __launch_bounds__(WAVES * 64)
void gemm_nt(const unsigned short* __restrict__ A,
             const unsigned short* __restrict__ Bm,
             unsigned short* __restrict__ out0,
             unsigned short* __restrict__ out1,
             unsigned short* __restrict__ out2,
             float* __restrict__ outf,
             int N)
{
    constexpr int BUFB  = 8192 + BN * 64;        // bytes per buffer (A + B)
    constexpr int NSTEP = 32;                    // K / 32
    constexpr int NA    = 8 / WAVES;             // A DMAs per wave per stage
    constexpr int NB    = BN / (16 * WAVES);     // B DMAs per wave per stage
    constexpr int BSL   = BN / 32;               // col sub-tiles per wave
    constexpr int MI    = 16 / WAVES;            // row sub-tiles per wave
    __shared__ unsigned char smem[3 * BUFB];
    const int K = 1024;
    const int tid  = threadIdx.x;
    const int wave = tid >> 6, lane = tid & 63;
    const int l15  = lane & 15, quad = lane >> 4;
    const int wm = wave >> 1, wn = wave & 1;

    int Lid = blockIdx.y * gridDim.x + blockIdx.x;
    int bm = (Lid & 7) * 4 + ((Lid >> 3) & 3);
    int bn = Lid >> 5;

    floatx4 acc[MI][BSL];
#pragma unroll
    for (int i = 0; i < MI; i++)
#pragma unroll
        for (int j = 0; j < BSL; j++)
            acc[i][j] = floatx4{0.f, 0.f, 0.f, 0.f};

    // staging maps: chunk s (16B units) -> LDS line L = s>>3, slot p = s&7.
    // content q = p ^ (L&7): global (Mrow = L*2 + (q>>2), Kblk = q&3).
    int soffA[NA], soffB[NB];
#pragma unroll
    for (int l = 0; l < NA; l++) {
        int s = (wave * NA + l) * 64 + lane;
        int L = s >> 3, q = (s & 7) ^ (L & 7);
        soffA[l] = (L * 2 + (q >> 2)) * K + (q & 3) * 8;
    }
#pragma unroll
    for (int l = 0; l < NB; l++) {
        int s = (wave * NB + l) * 64 + lane;
        int L = s >> 3, q = (s & 7) ^ (L & 7);
        soffB[l] = (L * 2 + (q >> 2)) * K + (q & 3) * 8;
    }
    // read maps: row r, K-block quad -> line r>>1, slot (((r&1)<<2)|quad)^(line&7)
    int aoff[MI], boff[BSL];
#pragma unroll
    for (int i = 0; i < MI; i++) {
        int r = wm * (MI * 16) + i * 16 + l15, L = r >> 1;
        aoff[i] = L * 128 + (((((r & 1) << 2) | quad) ^ (L & 7)) * 16);
    }
#pragma unroll
    for (int j = 0; j < BSL; j++) {
        int r = wn * (BN / 2) + j * 16 + l15, L = r >> 1;
        boff[j] = 8192 + L * 128 + (((((r & 1) << 2) | quad) ^ (L & 7)) * 16);
    }

    const unsigned short* Abase = A  + (size_t)(bm * 128) * K;
    const unsigned short* Bbase = Bm + (size_t)(bn * BN) * K;

    auto STAGE = [&](int u, int bufb) {
        const int k0 = u * 32;
#pragma unroll
        for (int l = 0; l < NA; l++)
            gl2lds16(Abase + (size_t)soffA[l] + k0, &smem[bufb + (wave * NA + l) * 1024]);
#pragma unroll
        for (int l = 0; l < NB; l++)
            gl2lds16(Bbase + (size_t)soffB[l] + k0, &smem[bufb + 8192 + (wave * NB + l) * 1024]);
    };

    // prologue: stages 0,1 into buffers 0,1
    STAGE(0, 0);
    STAGE(1, BUFB);

    int b0 = 0, b2 = 2;                          // compute buf, stage buf
    for (int t = 0; t < NSTEP; t++) {
        // barrier 1: all waves done computing step t-1 -> buf[b2] reusable
        asm volatile("" ::: "memory");
        __builtin_amdgcn_s_barrier();
        asm volatile("" ::: "memory");
        if (t + 2 < NSTEP) {
            STAGE(t + 2, b2 * BUFB);
            // retire stage(t); stages t+1,t+2 (2*(NA+NB)) stay in flight
            if (NA + NB == 2) asm volatile("s_waitcnt vmcnt(4)" ::: "memory");
            else              asm volatile("s_waitcnt vmcnt(6)" ::: "memory");
        } else if (t + 2 == NSTEP) {
            if (NA + NB == 2) asm volatile("s_waitcnt vmcnt(2)" ::: "memory");
            else              asm volatile("s_waitcnt vmcnt(3)" ::: "memory");
        } else {
            asm volatile("s_waitcnt vmcnt(0)" ::: "memory");
        }
        // barrier 2: tile t visible block-wide
        __builtin_amdgcn_s_barrier();
        asm volatile("" ::: "memory");

        const int cb = b0 * BUFB;
        short8 af[MI], bfr[BSL];
#pragma unroll
        for (int i = 0; i < MI; i++)
            af[i] = *(const short8*)(&smem[cb + aoff[i]]);
#pragma unroll
        for (int j = 0; j < BSL; j++)
            bfr[j] = *(const short8*)(&smem[cb + boff[j]]);
#pragma unroll
        for (int i = 0; i < MI; i++)
#pragma unroll
            for (int j = 0; j < BSL; j++)
                acc[i][j] = MFMA32(af[i], bfr[j], acc[i][j]);

        b0 = (b0 == 2) ? 0 : b0 + 1;
        b2 = (b2 == 2) ? 0 : b2 + 1;
    }

#pragma unroll
    for (int i = 0; i < MI; i++) {
#pragma unroll
        for (int j = 0; j < BSL; j++) {
            int n = bn * BN + wn * (BN / 2) + j * 16 + l15;
#pragma unroll
            for (int r = 0; r < 4; r++) {
                int m = bm * 128 + wm * (MI * 16) + i * 16 + quad * 4 + r;
                float fv = acc[i][j][r];
                if (MODE == 1) {
                    outf[(size_t)m * N + n] = fv;
                } else {
                    int t = n >> 10;            // 0=q 1=k 2=v
                    int h = (n >> 6) & 15;
                    int d = n & 63;
                    int b = m >> 11, si = m & 2047;
                    if (t == 2) {
                        // V^T with key interleave within 32-groups
                        int sip = (si & ~31) | (((si >> 2) & 3) << 3)
                                | (((si >> 4) & 1) << 2) | (si & 3);
                        out2[(((size_t)(b * 16 + h)) * 64 + d) * 2048 + sip] = f2bf(fv);
                    } else {
                        // q pre-scaled by 0.125*log2(e) (softmax fold)
                        if (t == 0) fv *= 0.18033688f;
                        size_t off = (((size_t)(b * 16 + h)) * 2048 + si) * 64 + d;
                        unsigned short* dst = (t == 0) ? out0 : out1;
                        dst[off] = f2bf(fv);
                    }
                }
            }
        }
    }
}

// ---------------------------------------------------------------------------
// Flash attention v15 (verified round 12: attn left the top-5, was 50.3us):
// KVBLK=64 on the v12 topology — 256-thread / 4-wave blocks, 32 q-rows per
// wave (128 q/block), grid 512, 2 blk/CU; barrier pairs 64/loop, 36 MFMA
// per wave per region, 16 batched ds_read_b128 per region.
// LDS 2 x (K 8KB + V 8KB) = 32KB; both tiles 64 x 128B rows with the
// verified row-XOR slot swizzle (0 conflicts). Staging pre-swizzles the
// GLOBAL source; LDS dest linear (gl2lds requirement).
// vmcnt ledger/wave (4 DMAs/stage, 4 mf loads): iter i: mf(4), barrier1,
// stage(i+1)(4), vmcnt(4) [retires stage(i)+mf(i), keeps stage(i+1)],
// barrier2, compute. Tail i=31: vmcnt(0). T5 setprio around MFMA clusters.
// q-split wave-complete softmax, full-K=32 PV via key-interleaved V^T,
// mask addend in QK C-init, Q pre-scaled by 0.125*log2e -> exp2 raw.
// ---------------------------------------------------------------------------
__global__ __launch_bounds__(256, 2)
void attn_kernel(const unsigned short* __restrict__ Qb,
                 const unsigned short* __restrict__ Kb,
                 const unsigned short* __restrict__ VbT,
                 const float* __restrict__ m2b,
                 const float* __restrict__ gateb,
                 unsigned short* __restrict__ ctx)
{
    __shared__ unsigned char smem[32768];        // 2 x (K 8KB + V 8KB)
    const int S = 2048;
    const int tid  = threadIdx.x;
    const int wave = tid >> 6, lane = tid & 63;
    const int l15  = lane & 15, quad = lane >> 4;

    int Lid = blockIdx.y * gridDim.x + blockIdx.x;
    int bh = (Lid & 7) * 4 + ((Lid >> 3) & 3);   // [0,32)
    int qc = Lid >> 5;                           // [0,16): 128 q-rows/block
    const int b = bh >> 4, h = bh & 15;
    const int q0 = qc * 128 + wave * 32;         // this wave's 32 q-rows

    const size_t headoff = (size_t)bh * S * 64;
    const unsigned short* Qh  = Qb  + headoff;   // [S][64] (pre-scaled)
    const unsigned short* Kh  = Kb  + headoff;   // [S][64]
    const unsigned short* VhT = VbT + headoff;   // [64][S'] key-interleaved
    const float* m2p = m2b + (size_t)b * S;

    // staging maps (s = (wave*2+l)*64 + lane covers 512 16B-chunks of each
    // 8KB section): line L = s>>3 (K: key row / V: d row, both 128B),
    // slot p = s&7, content chunk c = p^(L&7).
    // K src: (kb+L)*64 + c*8 ; V src: L*2048 + kb + c*8.
    int koff[2], voff[2];
#pragma unroll
    for (int l = 0; l < 2; l++) {
        int s = (wave * 2 + l) * 64 + lane;
        int L = s >> 3, c = (s & 7) ^ (L & 7);
        koff[l] = L * 64 + c * 8;
        voff[l] = L * 2048 + c * 8;
    }
    // read map (shared by K and V: 128B rows, row-XOR slots — verified
    // 0-conflict): row r=l15 within a 16-row subtile, col-chunk j:
    // qkoff[j] = l15*128 + ((j*4+quad) ^ (l15&7))*16 ; add kt*2048 (K) or
    // 8192 + dt*2048 (V).
    int qkoff[2];
#pragma unroll
    for (int j = 0; j < 2; j++)
        qkoff[j] = l15 * 128 + (((j * 4 + quad) ^ (l15 & 7)) * 16);

    // Q B-frags: aq[sub][s2] = Q[q0+sub*16+l15][s2*32+quad*8+..]
    short8 aq[2][2];
#pragma unroll
    for (int sub = 0; sub < 2; sub++)
#pragma unroll
        for (int s2 = 0; s2 < 2; s2++)
            aq[sub][s2] = *(const short8*)(Qh + (size_t)(q0 + sub * 16 + l15) * 64 + s2 * 32 + quad * 8);

    floatx4 o[2][4];                 // O^T partial [sub][dt]
    floatx4 lq[2];                   // l partial [sub]
#pragma unroll
    for (int sub = 0; sub < 2; sub++) {
        lq[sub] = floatx4{0.f, 0.f, 0.f, 0.f};
#pragma unroll
        for (int dt = 0; dt < 4; dt++) o[sub][dt] = floatx4{0.f, 0.f, 0.f, 0.f};
    }

    const uint4v onesu = {0x3F803F80u, 0x3F803F80u, 0x3F803F80u, 0x3F803F80u};
    const short8 ONES = __builtin_bit_cast(short8, onesu);

    // prologue: stage chunk 0 (keys 0..63) into buffer 0
#pragma unroll
    for (int l = 0; l < 2; l++) {
        gl2lds16(Kh + koff[l], &smem[(wave * 2 + l) * 1024]);
        gl2lds16(VhT + voff[l], &smem[8192 + (wave * 2 + l) * 1024]);
    }

    for (int i = 0; i < 32; i++) {
        const int cb = (i & 1) * 16384;
        const int nb = ((i + 1) & 1) * 16384;
        const int kb = i * 64;
        // mask addends for the 4 key sub-tiles (QK C-init: row == quad*4+r)
        floatx4 mf[4];
#pragma unroll
        for (int t = 0; t < 4; t++)
            mf[t] = *(const floatx4*)(m2p + kb + t * 16 + quad * 4);
        asm volatile("" ::: "memory");
        // barrier 1: all waves done reading buf[nb] (iter i-1)
        __builtin_amdgcn_s_barrier();
        asm volatile("" ::: "memory");
        if (i + 1 < 32) {
            const int kbn = (i + 1) * 64;
#pragma unroll
            for (int l = 0; l < 2; l++) {
                gl2lds16(Kh + (size_t)kbn * 64 + koff[l], &smem[nb + (wave * 2 + l) * 1024]);
                gl2lds16(VhT + kbn + voff[l], &smem[nb + 8192 + (wave * 2 + l) * 1024]);
            }
            // retire stage(i)+mf(i); stage(i+1)'s 4 stay in flight
            asm volatile("s_waitcnt vmcnt(4)" ::: "memory");
        } else {
            asm volatile("s_waitcnt vmcnt(0)" ::: "memory");
        }
        // barrier 2: whole chunk i visible block-wide
        __builtin_amdgcn_s_barrier();
        asm volatile("" ::: "memory");

        // K frags (consumed by QK before vf loads -> bounded reg pressure)
        short8 kf[4][2];
#pragma unroll
        for (int kt = 0; kt < 4; kt++)
#pragma unroll
            for (int s2 = 0; s2 < 2; s2++)
                kf[kt][s2] = *(const short8*)(&smem[cb + kt * 2048 + qkoff[s2]]);

        // QK for both subs: st[sub][kt], C init = mask addend
        floatx4 st[2][4];
        __builtin_amdgcn_s_setprio(1);
#pragma unroll
        for (int sub = 0; sub < 2; sub++)
#pragma unroll
            for (int kt = 0; kt < 4; kt++) {
                st[sub][kt] = MFMA32(kf[kt][0], aq[sub][0], mf[kt]);
                st[sub][kt] = MFMA32(kf[kt][1], aq[sub][1], st[sub][kt]);
            }
        __builtin_amdgcn_s_setprio(0);

        // V frags (128B-row swizzle, interleaved key positions)
        short8 vf[4][2];
#pragma unroll
        for (int dt = 0; dt < 4; dt++)
#pragma unroll
            for (int g = 0; g < 2; g++)
                vf[dt][g] = *(const short8*)(&smem[cb + 8192 + dt * 2048 + qkoff[g]]);

        // exp + pack (Q pre-scaled, mask in C-init): pf[sub][g] covers the
        // 32-key group g in interleave order {t0 e0..e3, t1 e0..e3}
        short8 pf[2][2];
#pragma unroll
        for (int sub = 0; sub < 2; sub++)
#pragma unroll
            for (int g = 0; g < 2; g++) {
                floatx4 a = st[sub][2 * g], c = st[sub][2 * g + 1];
                uint4v pu = {pack_bf2(EXP2(a[0]), EXP2(a[1])),
                             pack_bf2(EXP2(a[2]), EXP2(a[3])),
                             pack_bf2(EXP2(c[0]), EXP2(c[1])),
                             pack_bf2(EXP2(c[2]), EXP2(c[3]))};
                pf[sub][g] = __builtin_bit_cast(short8, pu);
            }

        // PV + l: full-K=32 per group, un-padded
        __builtin_amdgcn_s_setprio(1);
#pragma unroll
        for (int sub = 0; sub < 2; sub++)
#pragma unroll
            for (int g = 0; g < 2; g++) {
#pragma unroll
                for (int dt = 0; dt < 4; dt++)
                    o[sub][dt] = MFMA32(vf[dt][g], pf[sub][g], o[sub][dt]);
                lq[sub] = MFMA32(ONES, pf[sub][g], lq[sub]);
            }
        __builtin_amdgcn_s_setprio(0);
    }

    // epilogue: wave-complete softmax; lane writes q = q0+sub*16+l15, all dt
    float g = gateb[h];
#pragma unroll
    for (int sub = 0; sub < 2; sub++) {
        float iv = g / lq[sub][0];
        size_t base = ((size_t)(b * 2048 + q0 + sub * 16 + l15)) * 1024 + h * 64 + quad * 4;
#pragma unroll
        for (int dt = 0; dt < 4; dt++) {
            uint2v w;
            w[0] = pack_bf2(o[sub][dt][0] * iv, o[sub][dt][1] * iv);
            w[1] = pack_bf2(o[sub][dt][2] * iv, o[sub][dt][3] * iv);
            *(uint2v*)(ctx + base + dt * 16) = w;
        }
    }
}

// ---------------------------------------------------------------------------
extern "C" void kernel_launch(void* const* d_in, const int* in_sizes, int n_in,
                              void* d_out, int out_size, void* d_ws, size_t ws_size,
                              hipStream_t stream)
{
    const float* hidden = (const float*)d_in[0]; // [2,2048,1024] fp32
    const float* mask   = (const float*)d_in[1]; // [2,1,1,2048]  fp32
    const float* w_qkv  = (const float*)d_in[2]; // [3072,1024]   fp32
    const float* w_out  = (const float*)d_in[3]; // [1024,1024]   fp32
    const float* gate   = (const float*)d_in[4]; // [16]          fp32
    float* out = (float*)d_out;                  // [2,2048,1024] fp32

    unsigned short* q_buf = (unsigned short*)d_ws;   // [2,16,2048,64] bf16 (pre-scaled)
    unsigned short* k_buf = q_buf + 4194304;         // [2,16,2048,64]
    unsigned short* v_buf = k_buf + 4194304;         // [2,16,64,2048] (V^T, interleaved)
    unsigned short* c_buf = v_buf + 4194304;         // [2,2048,1024]  bf16
    unsigned short* h_bf  = c_buf + 4194304;         // hidden bf16
    unsigned short* wq_bf = h_bf  + 4194304;         // w_qkv bf16
    unsigned short* wo_bf = wq_bf + 3145728;         // w_out bf16
    float* m2_buf = (float*)(wo_bf + 1048576);       // [2,2048] fp32

    // one-pass prep: fp32->bf16 converts + mask transform
    cvt_all<<<8196, 256, 0, stream>>>(hidden, w_qkv, w_out, mask,
                                      h_bf, wq_bf, wo_bf, m2_buf);

    // QKV projection, scatter q(pre-scaled)/k/V^T(interleaved) — 8-wave blocks
    gemm_nt<0, 128, 8><<<dim3(24, 32), 512, 0, stream>>>(h_bf, wq_bf, q_buf, k_buf, v_buf, nullptr, 3072);
    // fused flash attention + gate -> ctx bf16 (128-q blocks of 4 waves, grid 512)
    attn_kernel<<<dim3(16, 32), 256, 0, stream>>>(q_buf, k_buf, v_buf, m2_buf, gate, c_buf);
    // output projection -> out fp32 (grid 16x32, 128x64 tiles) — 4-wave blocks
    gemm_nt<1, 64, 4><<<dim3(16, 32), 256, 0, stream>>>(c_buf, wo_bf, nullptr, nullptr, nullptr, out, 1024);
}